// Round 7
// baseline (310.250 us; speedup 1.0000x reference)
//
#include <hip/hip_runtime.h>

// ---------------- constants ----------------
#define HIDDEN 2048
#define NHEADS 16
#define NKV 4
#define HEAD_DIM 128
#define BB 2
#define TT 2048
#define MROWS (BB * TT)          // 4096
#define NQKV (NHEADS * HEAD_DIM + 2 * NKV * HEAD_DIM)  // 3072

typedef __attribute__((ext_vector_type(8))) short short8;
typedef __attribute__((ext_vector_type(4))) float f32x4;

#if __has_builtin(__builtin_amdgcn_exp2f)
#define EXP2F __builtin_amdgcn_exp2f
#else
#define EXP2F exp2f
#endif

__device__ __forceinline__ unsigned short f2bf(float f) {
    unsigned int u = __float_as_uint(f);
    unsigned int r = u + 0x7fffu + ((u >> 16) & 1u);
    return (unsigned short)(r >> 16);
}
__device__ __forceinline__ float b2f(unsigned short h) {
    return __uint_as_float(((unsigned int)h) << 16);
}

// async global->LDS, 16B per lane; lds dest = wave-uniform base + lane*16
__device__ __forceinline__ void load_lds_16(const void* g, void* l) {
    __builtin_amdgcn_global_load_lds((const __attribute__((address_space(1))) unsigned int*)g,
                                     (__attribute__((address_space(3))) unsigned int*)l,
                                     16, 0, 0);
}

// ---------------- cast x to bf16 ----------------
__global__ void cast_x_kernel(const float* __restrict__ x, unsigned short* __restrict__ xb) {
    int i = blockIdx.x * 256 + threadIdx.x;
    float4 v = ((const float4*)x)[i];
    ushort4 o;
    o.x = f2bf(v.x); o.y = f2bf(v.y); o.z = f2bf(v.z); o.w = f2bf(v.w);
    ((ushort4*)xb)[i] = o;
}

// ---------------- pack wq|wk|wv -> WqkvT (N=3072 rows, K=2048 cols), bf16 ----------------
__global__ void pack_wqkvT_kernel(const float* __restrict__ wq, const float* __restrict__ wk,
                                  const float* __restrict__ wv, unsigned short* __restrict__ out) {
    __shared__ float tile[32][33];
    int n0 = blockIdx.x * 32, k0 = blockIdx.y * 32;
    int tx = threadIdx.x, ty = threadIdx.y;
#pragma unroll
    for (int i = 0; i < 32; i += 8) {
        int k = k0 + ty + i;
        int n = n0 + tx;
        float v;
        if (n < 2048)      v = wq[(size_t)k * 2048 + n];
        else if (n < 2560) v = wk[(size_t)k * 512 + (n - 2048)];
        else               v = wv[(size_t)k * 512 + (n - 2560)];
        tile[ty + i][tx] = v;
    }
    __syncthreads();
#pragma unroll
    for (int i = 0; i < 32; i += 8) {
        int n = n0 + ty + i;
        int k = k0 + tx;
        out[(size_t)n * HIDDEN + k] = f2bf(tile[tx][ty + i]);
    }
}

// ---------------- transpose wo -> WoT (N=2048 rows, K=2048 cols), bf16 ----------------
__global__ void pack_woT_kernel(const float* __restrict__ wo, unsigned short* __restrict__ out) {
    __shared__ float tile[32][33];
    int n0 = blockIdx.x * 32, k0 = blockIdx.y * 32;
    int tx = threadIdx.x, ty = threadIdx.y;
#pragma unroll
    for (int i = 0; i < 32; i += 8)
        tile[ty + i][tx] = wo[(size_t)(k0 + ty + i) * HIDDEN + n0 + tx];
    __syncthreads();
#pragma unroll
    for (int i = 0; i < 32; i += 8)
        out[(size_t)(n0 + ty + i) * HIDDEN + k0 + tx] = f2bf(tile[tx][ty + i]);
}

// ---------------- GEMM1: 256x192 tile, BK=64, 8 waves (2Mx4N), 2 barriers/K-tile ----------
// Explicit 1-phase-ahead A-fragment register pipeline: ph+1's ds_reads issue
// BEFORE ph's MFMA cluster (separate named regs) -> counted lgkmcnt, LDS||MFMA overlap.
__global__ __launch_bounds__(512, 2) void gemm192_kernel(const unsigned short* __restrict__ A,
                                                         const unsigned short* __restrict__ Bt,
                                                         unsigned short* __restrict__ C) {
    const int N = NQKV, K = HIDDEN, NBX = 16;
    __shared__ __align__(16) unsigned short sA[2][256 * 64];  // 64 KB
    __shared__ __align__(16) unsigned short sB[2][192 * 64];  // 48 KB
    const int tid = threadIdx.x;
    const int lane = tid & 63, w = tid >> 6;
    const int quad = lane >> 4, l15 = lane & 15;
    const int wrM = w >> 2, wcN = w & 3;

    const int nwg = gridDim.x;
    const int bswz = (blockIdx.x & 7) * (nwg >> 3) + (blockIdx.x >> 3);
    const int m0 = (bswz / NBX) * 256;
    const int n0 = (bswz % NBX) * 192;

    const int lr = tid >> 3;                       // 0..63
    const int sc = (tid & 7) ^ (lr & 7);           // inverse-swizzled source chunk
    const unsigned short* gA = A + (size_t)(m0 + lr) * K + sc * 8;
    const unsigned short* gB = Bt + (size_t)(n0 + lr) * K + sc * 8;
    const size_t jstep = (size_t)64 * K;

    const int s0 = (quad ^ (l15 & 7)) * 8;
    const int s1 = ((4 | quad) ^ (l15 & 7)) * 8;

    f32x4 acc[8][3];
    const f32x4 z4 = {0.f, 0.f, 0.f, 0.f};
#pragma unroll
    for (int mi = 0; mi < 8; ++mi)
#pragma unroll
        for (int ni = 0; ni < 3; ++ni) acc[mi][ni] = z4;

    // prologue: stage K-tile 0 into buf 0 (7 issues: 4A + 3B)
#pragma unroll
    for (int j = 0; j < 4; ++j)
        load_lds_16(gA + (size_t)j * jstep, &sA[0][j * 4096 + w * 512]);
#pragma unroll
    for (int j = 0; j < 3; ++j)
        load_lds_16(gB + (size_t)j * jstep, &sB[0][j * 4096 + w * 512]);

    const int NT = K >> 6;
    for (int kt = 0; kt < NT; ++kt) {
        const int buf = kt & 1;
        const unsigned short* bA = &sA[buf][0];
        const unsigned short* bB = &sB[buf][0];

        __builtin_amdgcn_s_barrier();   // B1: everyone finished reading buf^1
        if (kt + 1 < NT) {
            const size_t kof = (size_t)(kt + 1) * 64;
#pragma unroll
            for (int j = 0; j < 4; ++j)
                load_lds_16(gA + (size_t)j * jstep + kof, &sA[buf ^ 1][j * 4096 + w * 512]);
#pragma unroll
            for (int j = 0; j < 3; ++j)
                load_lds_16(gB + (size_t)j * jstep + kof, &sB[buf ^ 1][j * 4096 + w * 512]);
            __asm__ volatile("s_waitcnt vmcnt(7)" ::: "memory");   // kt's staging done
        } else {
            __asm__ volatile("s_waitcnt vmcnt(0)" ::: "memory");
        }
        __builtin_amdgcn_s_barrier();   // B2: buf staged & visible

        // B fragments (reused all phases)
        short8 bf0[3], bf1[3];
#pragma unroll
        for (int ni = 0; ni < 3; ++ni) {
            const unsigned short* br = bB + (wcN * 48 + ni * 16 + l15) * 64;
            bf0[ni] = *(const short8*)(br + s0);
            bf1[ni] = *(const short8*)(br + s1);
        }
        // phase-0 A fragments (current set)
        short8 ac0[2], ac1[2];
#pragma unroll
        for (int mm = 0; mm < 2; ++mm) {
            const unsigned short* ar = bA + (wrM * 128 + mm * 16 + l15) * 64;
            ac0[mm] = *(const short8*)(ar + s0);
            ac1[mm] = *(const short8*)(ar + s1);
        }
#pragma unroll
        for (int ph = 0; ph < 4; ++ph) {
            short8 an0[2], an1[2];
            if (ph < 3) {   // issue ph+1's reads BEFORE ph's MFMAs
#pragma unroll
                for (int mm = 0; mm < 2; ++mm) {
                    const unsigned short* ar = bA + (wrM * 128 + ((ph + 1) * 2 + mm) * 16 + l15) * 64;
                    an0[mm] = *(const short8*)(ar + s0);
                    an1[mm] = *(const short8*)(ar + s1);
                }
            }
#pragma unroll
            for (int mm = 0; mm < 2; ++mm)
#pragma unroll
                for (int ni = 0; ni < 3; ++ni) {
                    acc[ph * 2 + mm][ni] =
                        __builtin_amdgcn_mfma_f32_16x16x32_bf16(ac0[mm], bf0[ni], acc[ph * 2 + mm][ni], 0, 0, 0);
                    acc[ph * 2 + mm][ni] =
                        __builtin_amdgcn_mfma_f32_16x16x32_bf16(ac1[mm], bf1[ni], acc[ph * 2 + mm][ni], 0, 0, 0);
                }
            if (ph < 3) {
#pragma unroll
                for (int mm = 0; mm < 2; ++mm) { ac0[mm] = an0[mm]; ac1[mm] = an1[mm]; }
            }
        }
    }

#pragma unroll
    for (int mi = 0; mi < 8; ++mi)
#pragma unroll
        for (int ni = 0; ni < 3; ++ni)
#pragma unroll
            for (int r = 0; r < 4; ++r) {
                int gr = m0 + wrM * 128 + mi * 16 + quad * 4 + r;
                int gc = n0 + wcN * 48 + ni * 16 + l15;
                C[(size_t)gr * N + gc] = f2bf(acc[mi][ni][r]);
            }
}

// ---------------- GEMM2: 256x128 tile (grid 256, full GPU), 8 waves (4Mx2N) ----------------
__global__ __launch_bounds__(512, 2) void gemm256n128_kernel(const unsigned short* __restrict__ A,
                                                             const unsigned short* __restrict__ Bt,
                                                             float* __restrict__ C,
                                                             int M, int N, int K, int NBX) {
    __shared__ __align__(16) unsigned short sA[2][256 * 64];  // 64 KB
    __shared__ __align__(16) unsigned short sB[2][128 * 64];  // 32 KB
    const int tid = threadIdx.x;
    const int lane = tid & 63, w = tid >> 6;
    const int quad = lane >> 4, l15 = lane & 15;
    const int wrM = w >> 1, wcN = w & 1;

    const int nwg = gridDim.x;
    const int bswz = (blockIdx.x & 7) * (nwg >> 3) + (blockIdx.x >> 3);
    const int m0 = (bswz / NBX) * 256;
    const int n0 = (bswz % NBX) * 128;

    const int lr = tid >> 3;
    const int sc = (tid & 7) ^ (lr & 7);
    const unsigned short* gA = A + (size_t)(m0 + lr) * K + sc * 8;
    const unsigned short* gB = Bt + (size_t)(n0 + lr) * K + sc * 8;
    const size_t jstep = (size_t)64 * K;

    const int s0 = (quad ^ (l15 & 7)) * 8;
    const int s1 = ((4 | quad) ^ (l15 & 7)) * 8;

    f32x4 acc[4][4];
    const f32x4 z4 = {0.f, 0.f, 0.f, 0.f};
#pragma unroll
    for (int mi = 0; mi < 4; ++mi)
#pragma unroll
        for (int ni = 0; ni < 4; ++ni) acc[mi][ni] = z4;

#pragma unroll
    for (int j = 0; j < 4; ++j)
        load_lds_16(gA + (size_t)j * jstep, &sA[0][j * 4096 + w * 512]);
#pragma unroll
    for (int j = 0; j < 2; ++j)
        load_lds_16(gB + (size_t)j * jstep, &sB[0][j * 4096 + w * 512]);

    const int NT = K >> 6;
    for (int kt = 0; kt < NT; ++kt) {
        const int buf = kt & 1;
        const unsigned short* bA = &sA[buf][0];
        const unsigned short* bB = &sB[buf][0];

        __builtin_amdgcn_s_barrier();   // B1
        if (kt + 1 < NT) {
            const size_t kof = (size_t)(kt + 1) * 64;
#pragma unroll
            for (int j = 0; j < 4; ++j)
                load_lds_16(gA + (size_t)j * jstep + kof, &sA[buf ^ 1][j * 4096 + w * 512]);
#pragma unroll
            for (int j = 0; j < 2; ++j)
                load_lds_16(gB + (size_t)j * jstep + kof, &sB[buf ^ 1][j * 4096 + w * 512]);
            __asm__ volatile("s_waitcnt vmcnt(6)" ::: "memory");
        } else {
            __asm__ volatile("s_waitcnt vmcnt(0)" ::: "memory");
        }
        __builtin_amdgcn_s_barrier();   // B2

        short8 bf0[4], bf1[4];
#pragma unroll
        for (int ni = 0; ni < 4; ++ni) {
            const unsigned short* br = bB + (wcN * 64 + ni * 16 + l15) * 64;
            bf0[ni] = *(const short8*)(br + s0);
            bf1[ni] = *(const short8*)(br + s1);
        }
        short8 ac0, ac1;
        {
            const unsigned short* ar = bA + (wrM * 64 + l15) * 64;
            ac0 = *(const short8*)(ar + s0);
            ac1 = *(const short8*)(ar + s1);
        }
#pragma unroll
        for (int ph = 0; ph < 4; ++ph) {
            short8 an0, an1;
            if (ph < 3) {
                const unsigned short* ar = bA + (wrM * 64 + (ph + 1) * 16 + l15) * 64;
                an0 = *(const short8*)(ar + s0);
                an1 = *(const short8*)(ar + s1);
            }
#pragma unroll
            for (int ni = 0; ni < 4; ++ni) {
                acc[ph][ni] = __builtin_amdgcn_mfma_f32_16x16x32_bf16(ac0, bf0[ni], acc[ph][ni], 0, 0, 0);
                acc[ph][ni] = __builtin_amdgcn_mfma_f32_16x16x32_bf16(ac1, bf1[ni], acc[ph][ni], 0, 0, 0);
            }
            if (ph < 3) { ac0 = an0; ac1 = an1; }
        }
    }

#pragma unroll
    for (int mi = 0; mi < 4; ++mi)
#pragma unroll
        for (int ni = 0; ni < 4; ++ni)
#pragma unroll
            for (int r = 0; r < 4; ++r) {
                int gr = m0 + wrM * 64 + mi * 16 + quad * 4 + r;
                int gc = n0 + wcN * 64 + ni * 16 + l15;
                C[(size_t)gr * N + gc] = acc[mi][ni][r];
            }
}

// ---------------- RoPE for Q,K (Q pre-scaled by 1/sqrt(d) * log2(e)) ----------------
#define QP (MROWS * NHEADS * 64)  // 4194304
#define KP (MROWS * NKV * 64)     // 1048576
#define QSCL (0.08838834764831845f * 1.4426950408889634f)
__global__ void rope_kernel(const unsigned short* __restrict__ qkv,
                            const float* __restrict__ cosb, const float* __restrict__ sinb,
                            unsigned short* __restrict__ Q, unsigned short* __restrict__ K) {
    int tid = blockIdx.x * 256 + threadIdx.x;
    if (tid < QP) {
        int d = tid & 63;
        int h = (tid >> 6) & 15;
        int row = tid >> 10;
        int t = row & (TT - 1), b = row >> 11;
        float x1 = b2f(qkv[(size_t)row * NQKV + h * 128 + d]);
        float x2 = b2f(qkv[(size_t)row * NQKV + h * 128 + d + 64]);
        float c = cosb[t * 64 + d], s = sinb[t * 64 + d];
        unsigned short* dst = Q + ((size_t)(b * NHEADS + h) * TT + t) * 128 + d;
        dst[0]  = f2bf((x1 * c - x2 * s) * QSCL);
        dst[64] = f2bf((x2 * c + x1 * s) * QSCL);
    } else {
        int p = tid - QP;
        int d = p & 63;
        int kh = (p >> 6) & 3;
        int row = p >> 8;
        int t = row & (TT - 1), b = row >> 11;
        float x1 = b2f(qkv[(size_t)row * NQKV + 2048 + kh * 128 + d]);
        float x2 = b2f(qkv[(size_t)row * NQKV + 2048 + kh * 128 + d + 64]);
        float c = cosb[t * 64 + d], s = sinb[t * 64 + d];
        unsigned short* dst = K + ((size_t)(b * NKV + kh) * TT + t) * 128 + d;
        dst[0]  = f2bf(x1 * c - x2 * s);
        dst[64] = f2bf(x2 * c + x1 * s);
    }
}

// ---------------- V transpose: qkv -> Vt[b][kvh][d][T] ----------------
__global__ void vtrans_kernel(const unsigned short* __restrict__ qkv,
                              unsigned short* __restrict__ Vt) {
    __shared__ unsigned short tile[32][33];
    int t0 = blockIdx.x * 32, d0 = blockIdx.y * 32, bz = blockIdx.z;  // bz = b*NKV+kh
    int b = bz >> 2, kh = bz & 3;
    int tx = threadIdx.x, ty = threadIdx.y;
#pragma unroll
    for (int i = 0; i < 32; i += 8)
        tile[ty + i][tx] = qkv[(size_t)(b * TT + t0 + ty + i) * NQKV + 2560 + kh * 128 + d0 + tx];
    __syncthreads();
#pragma unroll
    for (int i = 0; i < 32; i += 8)
        Vt[((size_t)bz * 128 + d0 + ty + i) * TT + t0 + tx] = tile[tx][ty + i];
}

// ---------------- flash attention: trio grid, 48 KB LDS (3 blk/CU), reg-P via shfl ----------
__global__ __launch_bounds__(256, 3) void flash_kernel(const unsigned short* __restrict__ Qb,
                                                       const unsigned short* __restrict__ Kb,
                                                       const unsigned short* __restrict__ Vtb,
                                                       unsigned short* __restrict__ Ob,
                                                       unsigned short* __restrict__ Po,
                                                       float* __restrict__ Pl) {
    __shared__ __align__(16) unsigned short sK[2][64 * 128];  // [buf][kv][d] 32 KB
    __shared__ __align__(16) unsigned short sV[128 * 64];     // [d][kv]      16 KB

    const int tid = threadIdx.x;
    const int w = tid >> 6, lane = tid & 63;
    const int quad = lane >> 4, l15 = lane & 15;
    const int r7 = l15 & 7;

    const int lin = blockIdx.x;
    const int member = lin >> 8;
    const int rem = lin & 255;
    const int h = rem & 15;
    const int b = (rem >> 4) & 1;
    const int j = rem >> 5;           // 0..7
    int qb, kvlo, kvhi;
    bool partial;
    if (member == 2) {
        qb = j; kvlo = 0; kvhi = (qb + 1) * 128; partial = false;
    } else {
        qb = 15 - j;
        int half = (qb + 1) * 64;
        kvlo = member ? half : 0;
        kvhi = member ? (qb + 1) * 128 : half;
        partial = true;
    }
    const int q0 = qb * 128;
    const int ntile = (kvhi - kvlo) >> 6;
    const int kvh = h >> 2;
    const unsigned short* Qh = Qb + (size_t)(b * NHEADS + h) * TT * 128;
    const unsigned short* Kh = Kb + (size_t)(b * NKV + kvh) * TT * 128;
    const unsigned short* Vth = Vtb + (size_t)(b * NKV + kvh) * 128 * TT;

    const int wrow0 = q0 + w * 32;

    const int kr = lane >> 4;
    const unsigned short* gKe = Kh + (size_t)(w * 16 + kr) * 128 + (((lane & 15) ^ kr) * 8);
    const unsigned short* gKo = Kh + (size_t)(w * 16 + 4 + kr) * 128 + (((lane & 15) ^ (4 + kr)) * 8);
    const int vr = lane >> 3;
    const unsigned short* gV0 = Vth + (size_t)(w * 32 + vr) * TT + (((lane & 7) ^ vr) * 8);

    short8 aq[2][4];
#pragma unroll
    for (int mi = 0; mi < 2; ++mi)
#pragma unroll
        for (int dk = 0; dk < 4; ++dk)
            aq[mi][dk] = *(const short8*)(Qh + (size_t)(wrow0 + mi * 16 + l15) * 128 + dk * 32 + quad * 8);

    f32x4 accO[2][8];
    float accLc[2] = {0.f, 0.f};
    const f32x4 z4 = {0.f, 0.f, 0.f, 0.f};
#pragma unroll
    for (int mi = 0; mi < 2; ++mi)
#pragma unroll
        for (int nb = 0; nb < 8; ++nb) accO[mi][nb] = z4;

    // prologue: K(first tile) -> sK[0]
#pragma unroll
    for (int g = 0; g < 4; ++g) {
        const unsigned short* src = (g & 1) ? gKo : gKe;
        load_lds_16(src + (size_t)(kvlo + (g >> 1) * 8) * 128, &sK[0][(w * 4 + g) * 512]);
    }

    for (int it = 0; it < ntile; ++it) {
        const int cur = it & 1;
        const int kv0 = kvlo + it * 64;
        __asm__ volatile("s_waitcnt vmcnt(0)" ::: "memory");
        __builtin_amdgcn_s_barrier();
#pragma unroll
        for (int g = 0; g < 4; ++g)
            load_lds_16(gV0 + (size_t)(g * 8) * TT + kv0, &sV[(w * 4 + g) * 512]);
        const bool hasn = (it + 1 < ntile);
        if (hasn) {
#pragma unroll
            for (int g = 0; g < 4; ++g) {
                const unsigned short* src = (g & 1) ? gKo : gKe;
                load_lds_16(src + (size_t)(kv0 + 64 + (g >> 1) * 8) * 128, &sK[cur ^ 1][(w * 4 + g) * 512]);
            }
        }
        const bool compute = (kv0 <= wrow0 + 31);  // wave-uniform
        short8 ap[2][2];
        if (compute) {
            f32x4 st[4][2];
#pragma unroll
            for (int t = 0; t < 4; ++t)
#pragma unroll
                for (int h2 = 0; h2 < 2; ++h2) st[t][h2] = z4;
            __builtin_amdgcn_s_setprio(1);
#pragma unroll
            for (int t = 0; t < 4; ++t) {
#pragma unroll
                for (int dk = 0; dk < 4; ++dk) {
                    short8 ak = *(const short8*)(&sK[cur][(t * 16 + l15) * 128 + ((dk * 4 + quad) ^ r7) * 8]);
                    st[t][0] = __builtin_amdgcn_mfma_f32_16x16x32_bf16(ak, aq[0][dk], st[t][0], 0, 0, 0);
                    st[t][1] = __builtin_amdgcn_mfma_f32_16x16x32_bf16(ak, aq[1][dk], st[t][1], 0, 0, 0);
                }
            }
            __builtin_amdgcn_s_setprio(0);
            unsigned int pk32[4][2][2];
#pragma unroll
            for (int h2 = 0; h2 < 2; ++h2) {
                const int qg = wrow0 + h2 * 16 + l15;
#pragma unroll
                for (int t = 0; t < 4; ++t) {
                    const int kvb = kv0 + t * 16 + quad * 4;
                    const bool nm = (kv0 + t * 16 + 15) > (wrow0 + h2 * 16);
                    float pv[4];
#pragma unroll
                    for (int r = 0; r < 4; ++r) {
                        float p = EXP2F(st[t][h2][r]);
                        if (nm) p = (kvb + r <= qg) ? p : 0.f;
                        pv[r] = p;
                    }
                    accLc[h2] += (pv[0] + pv[1]) + (pv[2] + pv[3]);
                    __asm__("v_cvt_pk_bf16_f32 %0, %1, %2" : "=v"(pk32[t][h2][0]) : "v"(pv[0]), "v"(pv[1]));
                    __asm__("v_cvt_pk_bf16_f32 %0, %1, %2" : "=v"(pk32[t][h2][1]) : "v"(pv[2]), "v"(pv[3]));
                }
            }
#pragma unroll
            for (int h2 = 0; h2 < 2; ++h2)
#pragma unroll
                for (int kf = 0; kf < 2; ++kf) {
                    union { unsigned int u[4]; short8 s8; } W;
#pragma unroll
                    for (int wdx = 0; wdx < 4; ++wdx) {
                        int srcl = (2 * (quad & 1) + (wdx >> 1)) * 16 + l15;
                        unsigned int a0 = (unsigned int)__shfl((int)pk32[2 * kf][h2][wdx & 1], srcl, 64);
                        unsigned int a1 = (unsigned int)__shfl((int)pk32[2 * kf + 1][h2][wdx & 1], srcl, 64);
                        W.u[wdx] = (quad >> 1) ? a1 : a0;
                    }
                    ap[h2][kf] = W.s8;
                }
        }
        if (hasn) { __asm__ volatile("s_waitcnt vmcnt(4)" ::: "memory"); }
        else      { __asm__ volatile("s_waitcnt vmcnt(0)" ::: "memory"); }
        __builtin_amdgcn_s_barrier();
        if (compute) {
            __builtin_amdgcn_s_setprio(1);
#pragma unroll
            for (int nb = 0; nb < 8; ++nb) {
                short8 bv0 = *(const short8*)(&sV[(nb * 16 + l15) * 64 + ((quad) ^ r7) * 8]);
                short8 bv1 = *(const short8*)(&sV[(nb * 16 + l15) * 64 + ((4 + quad) ^ r7) * 8]);
#pragma unroll
                for (int mi = 0; mi < 2; ++mi) {
                    accO[mi][nb] = __builtin_amdgcn_mfma_f32_16x16x32_bf16(ap[mi][0], bv0, accO[mi][nb], 0, 0, 0);
                    accO[mi][nb] = __builtin_amdgcn_mfma_f32_16x16x32_bf16(ap[mi][1], bv1, accO[mi][nb], 0, 0, 0);
                }
            }
            __builtin_amdgcn_s_setprio(0);
        }
    }

    float Lr[2][4];
#pragma unroll
    for (int mi = 0; mi < 2; ++mi) {
        float v = accLc[mi];
        v += __shfl_xor(v, 16, 64);
        v += __shfl_xor(v, 32, 64);
#pragma unroll
        for (int r = 0; r < 4; ++r)
            Lr[mi][r] = __shfl(v, quad * 4 + r, 64);
    }

    __syncthreads();
    unsigned short* sPw = &sV[0] + w * 2048;

    if (!partial) {
        float inv[2][4];
#pragma unroll
        for (int mi = 0; mi < 2; ++mi)
#pragma unroll
            for (int r = 0; r < 4; ++r) inv[mi][r] = 1.0f / Lr[mi][r];
        const size_t obase = ((size_t)b * TT + wrow0) * (NHEADS * HEAD_DIM) + h * 128;
#pragma unroll
        for (int half = 0; half < 2; ++half) {
            __asm__ volatile("s_waitcnt lgkmcnt(0)" ::: "memory");
#pragma unroll
            for (int mi = 0; mi < 2; ++mi)
#pragma unroll
                for (int nb2 = 0; nb2 < 4; ++nb2)
#pragma unroll
                    for (int r = 0; r < 4; ++r) {
                        const int row = mi * 16 + quad * 4 + r;
                        sPw[row * 64 + (((2 * nb2 + (l15 >> 3)) ^ (row & 7)) * 8) + r7] =
                            f2bf(accO[mi][half * 4 + nb2][r] * inv[mi][r]);
                    }
            __asm__ volatile("s_waitcnt lgkmcnt(0)" ::: "memory");
#pragma unroll
            for (int pass = 0; pass < 4; ++pass) {
                int row2 = pass * 8 + (lane >> 3);
                short8 vv = *(const short8*)(&sPw[row2 * 64 + (((lane & 7) ^ (row2 & 7)) * 8)]);
                *(short8*)(Ob + obase + (size_t)row2 * (NHEADS * HEAD_DIM) + half * 64 + (lane & 7) * 8) = vv;
            }
        }
    } else {
        const size_t pbase = ((size_t)(member * 2 + b) * 1024 + (wrow0 - 1024)) * 2048 + h * 128;
#pragma unroll
        for (int half = 0; half < 2; ++half) {
            __asm__ volatile("s_waitcnt lgkmcnt(0)" ::: "memory");
#pragma unroll
            for (int mi = 0; mi < 2; ++mi)
#pragma unroll
                for (int nb2 = 0; nb2 < 4; ++nb2)
#pragma unroll
                    for (int r = 0; r < 4; ++r) {
                        const int row = mi * 16 + quad * 4 + r;
                        sPw[row * 64 + (((2 * nb2 + (l15 >> 3)) ^ (row & 7)) * 8) + r7] =
                            f2bf(accO[mi][half * 4 + nb2][r]);
                    }
            __asm__ volatile("s_waitcnt lgkmcnt(0)" ::: "memory");
#pragma unroll
            for (int pass = 0; pass < 4; ++pass) {
                int row2 = pass * 8 + (lane >> 3);
                short8 vv = *(const short8*)(&sPw[row2 * 64 + (((lane & 7) ^ (row2 & 7)) * 8)]);
                *(short8*)(Po + pbase + (size_t)row2 * 2048 + half * 64 + (lane & 7) * 8) = vv;
            }
        }
        float* plb = Pl + ((size_t)(member * 2 + b) * 16 + h) * 1024 + (wrow0 - 1024);
        if (l15 == 0) {
#pragma unroll
            for (int mi = 0; mi < 2; ++mi)
#pragma unroll
                for (int r = 0; r < 4; ++r)
                    plb[mi * 16 + quad * 4 + r] = Lr[mi][r];
        }
    }
}

// ---------------- merge: attn[rows 1024..2047] = (O0+O1)/(L0+L1) ----------------
__global__ void merge_kernel(const unsigned short* __restrict__ Po, const float* __restrict__ Pl,
                             unsigned short* __restrict__ attn) {
    int gid = blockIdx.x * 256 + threadIdx.x;
    size_t e8 = (size_t)gid * 8;
    int col = (int)(e8 & 2047);
    int rl  = (int)((e8 >> 11) & 1023);
    int b   = (int)(e8 >> 21);
    int h   = col >> 7;
    size_t i0 = ((size_t)b * 1024 + rl) * 2048 + col;            // part 0
    size_t i1 = ((size_t)(2 + b) * 1024 + rl) * 2048 + col;      // part 1
    float l = Pl[((size_t)b * 16 + h) * 1024 + rl] + Pl[((size_t)(2 + b) * 16 + h) * 1024 + rl];
    float inv = 1.0f / l;
    union { uint4 v; unsigned short u[8]; } a, c, o;
    a.v = *(const uint4*)(Po + i0);
    c.v = *(const uint4*)(Po + i1);
#pragma unroll
    for (int k = 0; k < 8; ++k)
        o.u[k] = f2bf((b2f(a.u[k]) + b2f(c.u[k])) * inv);
    *(uint4*)(attn + ((size_t)b * 2048 + 1024 + rl) * 2048 + col) = o.v;
}

// ---------------- launch ----------------
extern "C" void kernel_launch(void* const* d_in, const int* in_sizes, int n_in,
                              void* d_out, int out_size, void* d_ws, size_t ws_size,
                              hipStream_t stream) {
    const float* x    = (const float*)d_in[0];
    const float* cosb = (const float*)d_in[1];
    const float* sinb = (const float*)d_in[2];
    const float* wq   = (const float*)d_in[3];
    const float* wk   = (const float*)d_in[4];
    const float* wv   = (const float*)d_in[5];
    const float* wo   = (const float*)d_in[6];
    float* out = (float*)d_out;

    char* ws = (char*)d_ws;
    unsigned short* xb    = (unsigned short*)(ws);                       // 16 MB (dead after gemm1)
    unsigned short* wqkvT = (unsigned short*)(ws + (16u << 20));         // 12 MB (dead after gemm1)
    unsigned short* woT   = (unsigned short*)(ws + (28u << 20));         // 8 MB
    unsigned short* qkv   = (unsigned short*)(ws + (36u << 20));         // 24 MB
    unsigned short* Qbuf  = (unsigned short*)(ws + (60u << 20));         // 16 MB
    unsigned short* Kbuf  = (unsigned short*)(ws + (76u << 20));         // 4 MB
    unsigned short* Vt    = (unsigned short*)(ws + (80u << 20));         // 4 MB
    unsigned short* attn  = (unsigned short*)(ws + (84u << 20));         // 16 MB -> 100 MB total
    // overlays (regions dead by the time flash runs):
    unsigned short* Po    = (unsigned short*)(ws);                       // 16 MB partial O (over xb)
    float*          Pl    = (float*)(ws + (16u << 20));                  // 512 KB partial L (over wqkvT)

    cast_x_kernel<<<(MROWS * HIDDEN) / 4 / 256, 256, 0, stream>>>(x, xb);
    pack_wqkvT_kernel<<<dim3(NQKV / 32, HIDDEN / 32), dim3(32, 8), 0, stream>>>(wq, wk, wv, wqkvT);
    pack_woT_kernel<<<dim3(HIDDEN / 32, HIDDEN / 32), dim3(32, 8), 0, stream>>>(wo, woT);

    // GEMM1: 4096x3072x2048 -> 256x192 tiles = 16x16 = 256 blocks (full GPU, %8==0)
    gemm192_kernel<<<dim3(256), 512, 0, stream>>>(xb, wqkvT, qkv);

    rope_kernel<<<(QP + KP) / 256, 256, 0, stream>>>(qkv, cosb, sinb, Qbuf, Kbuf);
    vtrans_kernel<<<dim3(TT / 32, HEAD_DIM / 32, BB * NKV), dim3(32, 8), 0, stream>>>(qkv, Vt);

    // flash: trio grid 768 (members 0/1 partial halves, member 2 direct), 3 blocks/CU
    flash_kernel<<<dim3(768), 256, 0, stream>>>(Qbuf, Kbuf, Vt, attn, Po, Pl);
    merge_kernel<<<dim3(2048), 256, 0, stream>>>(Po, Pl, attn);

    // GEMM2: 4096x2048x2048 -> 256x128 tiles = 16x16 = 256 blocks (full GPU, %8==0)
    gemm256n128_kernel<<<dim3((MROWS / 256) * (HIDDEN / 128)), 512, 0, stream>>>(
        attn, woT, out, MROWS, HIDDEN, HIDDEN, HIDDEN / 128);
}

// Round 8
// 304.293 us; speedup vs baseline: 1.0196x; 1.0196x over previous
//
#include <hip/hip_runtime.h>

// ---------------- constants ----------------
#define HIDDEN 2048
#define NHEADS 16
#define NKV 4
#define HEAD_DIM 128
#define BB 2
#define TT 2048
#define MROWS (BB * TT)          // 4096
#define NQKV (NHEADS * HEAD_DIM + 2 * NKV * HEAD_DIM)  // 3072

typedef __attribute__((ext_vector_type(8))) short short8;
typedef __attribute__((ext_vector_type(4))) float f32x4;

#if __has_builtin(__builtin_amdgcn_exp2f)
#define EXP2F __builtin_amdgcn_exp2f
#else
#define EXP2F exp2f
#endif

__device__ __forceinline__ unsigned short f2bf(float f) {
    unsigned int u = __float_as_uint(f);
    unsigned int r = u + 0x7fffu + ((u >> 16) & 1u);
    return (unsigned short)(r >> 16);
}
__device__ __forceinline__ float b2f(unsigned short h) {
    return __uint_as_float(((unsigned int)h) << 16);
}

// async global->LDS, 16B per lane; lds dest = wave-uniform base + lane*16
__device__ __forceinline__ void load_lds_16(const void* g, void* l) {
    __builtin_amdgcn_global_load_lds((const __attribute__((address_space(1))) unsigned int*)g,
                                     (__attribute__((address_space(3))) unsigned int*)l,
                                     16, 0, 0);
}

// ---------------- cast x to bf16 ----------------
__global__ void cast_x_kernel(const float* __restrict__ x, unsigned short* __restrict__ xb) {
    int i = blockIdx.x * 256 + threadIdx.x;
    float4 v = ((const float4*)x)[i];
    ushort4 o;
    o.x = f2bf(v.x); o.y = f2bf(v.y); o.z = f2bf(v.z); o.w = f2bf(v.w);
    ((ushort4*)xb)[i] = o;
}

// ---------------- pack wq|wk|wv -> WqkvT (N=3072 rows, K=2048 cols), bf16 ----------------
__global__ void pack_wqkvT_kernel(const float* __restrict__ wq, const float* __restrict__ wk,
                                  const float* __restrict__ wv, unsigned short* __restrict__ out) {
    __shared__ float tile[32][33];
    int n0 = blockIdx.x * 32, k0 = blockIdx.y * 32;
    int tx = threadIdx.x, ty = threadIdx.y;
#pragma unroll
    for (int i = 0; i < 32; i += 8) {
        int k = k0 + ty + i;
        int n = n0 + tx;
        float v;
        if (n < 2048)      v = wq[(size_t)k * 2048 + n];
        else if (n < 2560) v = wk[(size_t)k * 512 + (n - 2048)];
        else               v = wv[(size_t)k * 512 + (n - 2560)];
        tile[ty + i][tx] = v;
    }
    __syncthreads();
#pragma unroll
    for (int i = 0; i < 32; i += 8) {
        int n = n0 + ty + i;
        int k = k0 + tx;
        out[(size_t)n * HIDDEN + k] = f2bf(tile[tx][ty + i]);
    }
}

// ---------------- transpose wo -> WoT (N=2048 rows, K=2048 cols), bf16 ----------------
__global__ void pack_woT_kernel(const float* __restrict__ wo, unsigned short* __restrict__ out) {
    __shared__ float tile[32][33];
    int n0 = blockIdx.x * 32, k0 = blockIdx.y * 32;
    int tx = threadIdx.x, ty = threadIdx.y;
#pragma unroll
    for (int i = 0; i < 32; i += 8)
        tile[ty + i][tx] = wo[(size_t)(k0 + ty + i) * HIDDEN + n0 + tx];
    __syncthreads();
#pragma unroll
    for (int i = 0; i < 32; i += 8)
        out[(size_t)(n0 + ty + i) * HIDDEN + k0 + tx] = f2bf(tile[tx][ty + i]);
}

// ---------------- GEMM1: 256x192, BK=64, 8 waves (2Mx4N), m201-style 4-phase schedule -----
// Per phase: {ds_read frags | 1-2 staging issues for kt+1 | counted vmcnt (ph1/ph3) |
// barrier | lgkmcnt(0) | setprio 12xMFMA | barrier}. Staging order Bj0,Bj1,Bj2,Aj0,
// Aj2,Aj1,Aj3 so every region lands >=1.5 phases before first read. vmcnt(4)@ph1
// retires THIS tile's Aj1,Aj3 (read in ph2/ph3); vmcnt(2)@ph3 retires next tile's
// Bj*+Aj0+Aj2 (read in its ph0/ph1). Never drains in steady state.
__global__ __launch_bounds__(512, 2) void gemm192_kernel(const unsigned short* __restrict__ A,
                                                         const unsigned short* __restrict__ Bt,
                                                         unsigned short* __restrict__ C) {
    const int N = NQKV, K = HIDDEN, NBX = 16;
    __shared__ __align__(16) unsigned short sA[2][256 * 64];  // 64 KB
    __shared__ __align__(16) unsigned short sB[2][192 * 64];  // 48 KB
    const int tid = threadIdx.x;
    const int lane = tid & 63, w = tid >> 6;
    const int quad = lane >> 4, l15 = lane & 15;
    const int wrM = w >> 2, wcN = w & 3;

    const int nwg = gridDim.x;
    const int bswz = (blockIdx.x & 7) * (nwg >> 3) + (blockIdx.x >> 3);
    const int m0 = (bswz / NBX) * 256;
    const int n0 = (bswz % NBX) * 192;

    const int lr = tid >> 3;                       // 0..63
    const int sc = (tid & 7) ^ (lr & 7);           // inverse-swizzled source chunk
    const unsigned short* gA = A + (size_t)(m0 + lr) * K + sc * 8;
    const unsigned short* gB = Bt + (size_t)(n0 + lr) * K + sc * 8;
    const size_t jstep = (size_t)64 * K;

    const int s0 = (quad ^ (l15 & 7)) * 8;
    const int s1 = ((4 | quad) ^ (l15 & 7)) * 8;

    f32x4 acc[8][3];
    const f32x4 z4 = {0.f, 0.f, 0.f, 0.f};
#pragma unroll
    for (int mi = 0; mi < 8; ++mi)
#pragma unroll
        for (int ni = 0; ni < 3; ++ni) acc[mi][ni] = z4;

    // prologue: tile 0 in steady-state order; vmcnt(2) leaves Aj1,Aj3 in flight
    load_lds_16(gB + (size_t)0 * jstep, &sB[0][0 * 4096 + w * 512]);
    load_lds_16(gB + (size_t)1 * jstep, &sB[0][1 * 4096 + w * 512]);
    load_lds_16(gB + (size_t)2 * jstep, &sB[0][2 * 4096 + w * 512]);
    load_lds_16(gA + (size_t)0 * jstep, &sA[0][0 * 4096 + w * 512]);
    load_lds_16(gA + (size_t)2 * jstep, &sA[0][2 * 4096 + w * 512]);
    load_lds_16(gA + (size_t)1 * jstep, &sA[0][1 * 4096 + w * 512]);
    load_lds_16(gA + (size_t)3 * jstep, &sA[0][3 * 4096 + w * 512]);
    __asm__ volatile("s_waitcnt vmcnt(2)" ::: "memory");
    __builtin_amdgcn_s_barrier();

    const int NT = K >> 6;
    for (int kt = 0; kt < NT; ++kt) {
        const int buf = kt & 1, nxt = buf ^ 1;
        const unsigned short* bA = &sA[buf][0];
        const unsigned short* bB = &sB[buf][0];
        const bool hasn = (kt + 1 < NT);
        const size_t kof = (size_t)(kt + 1) * 64;

        // ================= phase 0 =================
        short8 bf0[3], bf1[3];
#pragma unroll
        for (int ni = 0; ni < 3; ++ni) {
            const unsigned short* br = bB + (wcN * 48 + ni * 16 + l15) * 64;
            bf0[ni] = *(const short8*)(br + s0);
            bf1[ni] = *(const short8*)(br + s1);
        }
        short8 a00[2], a01[2];
#pragma unroll
        for (int mm = 0; mm < 2; ++mm) {
            const unsigned short* ar = bA + (wrM * 128 + mm * 16 + l15) * 64;
            a00[mm] = *(const short8*)(ar + s0);
            a01[mm] = *(const short8*)(ar + s1);
        }
        if (hasn) {
            load_lds_16(gB + (size_t)0 * jstep + kof, &sB[nxt][0 * 4096 + w * 512]);
            load_lds_16(gB + (size_t)1 * jstep + kof, &sB[nxt][1 * 4096 + w * 512]);
        }
        __builtin_amdgcn_s_barrier();
        __asm__ volatile("s_waitcnt lgkmcnt(0)" ::: "memory");
        __builtin_amdgcn_s_setprio(1);
#pragma unroll
        for (int mm = 0; mm < 2; ++mm)
#pragma unroll
            for (int ni = 0; ni < 3; ++ni) {
                acc[mm][ni] = __builtin_amdgcn_mfma_f32_16x16x32_bf16(a00[mm], bf0[ni], acc[mm][ni], 0, 0, 0);
                acc[mm][ni] = __builtin_amdgcn_mfma_f32_16x16x32_bf16(a01[mm], bf1[ni], acc[mm][ni], 0, 0, 0);
            }
        __builtin_amdgcn_s_setprio(0);
        __builtin_amdgcn_s_barrier();

        // ================= phase 1 =================
        short8 a10[2], a11[2];
#pragma unroll
        for (int mm = 0; mm < 2; ++mm) {
            const unsigned short* ar = bA + (wrM * 128 + (2 + mm) * 16 + l15) * 64;
            a10[mm] = *(const short8*)(ar + s0);
            a11[mm] = *(const short8*)(ar + s1);
        }
        if (hasn) {
            load_lds_16(gB + (size_t)2 * jstep + kof, &sB[nxt][2 * 4096 + w * 512]);
            load_lds_16(gA + (size_t)0 * jstep + kof, &sA[nxt][0 * 4096 + w * 512]);
            __asm__ volatile("s_waitcnt vmcnt(4)" ::: "memory");  // retires THIS tile's Aj1,Aj3
        } else {
            __asm__ volatile("s_waitcnt vmcnt(0)" ::: "memory");
        }
        __builtin_amdgcn_s_barrier();
        __asm__ volatile("s_waitcnt lgkmcnt(0)" ::: "memory");
        __builtin_amdgcn_s_setprio(1);
#pragma unroll
        for (int mm = 0; mm < 2; ++mm)
#pragma unroll
            for (int ni = 0; ni < 3; ++ni) {
                acc[2 + mm][ni] = __builtin_amdgcn_mfma_f32_16x16x32_bf16(a10[mm], bf0[ni], acc[2 + mm][ni], 0, 0, 0);
                acc[2 + mm][ni] = __builtin_amdgcn_mfma_f32_16x16x32_bf16(a11[mm], bf1[ni], acc[2 + mm][ni], 0, 0, 0);
            }
        __builtin_amdgcn_s_setprio(0);
        __builtin_amdgcn_s_barrier();

        // ================= phase 2 =================
        short8 a20[2], a21[2];
#pragma unroll
        for (int mm = 0; mm < 2; ++mm) {
            const unsigned short* ar = bA + (wrM * 128 + (4 + mm) * 16 + l15) * 64;
            a20[mm] = *(const short8*)(ar + s0);
            a21[mm] = *(const short8*)(ar + s1);
        }
        if (hasn) {
            load_lds_16(gA + (size_t)2 * jstep + kof, &sA[nxt][2 * 4096 + w * 512]);
            load_lds_16(gA + (size_t)1 * jstep + kof, &sA[nxt][1 * 4096 + w * 512]);
        }
        __builtin_amdgcn_s_barrier();
        __asm__ volatile("s_waitcnt lgkmcnt(0)" ::: "memory");
        __builtin_amdgcn_s_setprio(1);
#pragma unroll
        for (int mm = 0; mm < 2; ++mm)
#pragma unroll
            for (int ni = 0; ni < 3; ++ni) {
                acc[4 + mm][ni] = __builtin_amdgcn_mfma_f32_16x16x32_bf16(a20[mm], bf0[ni], acc[4 + mm][ni], 0, 0, 0);
                acc[4 + mm][ni] = __builtin_amdgcn_mfma_f32_16x16x32_bf16(a21[mm], bf1[ni], acc[4 + mm][ni], 0, 0, 0);
            }
        __builtin_amdgcn_s_setprio(0);
        __builtin_amdgcn_s_barrier();

        // ================= phase 3 =================
        short8 a30[2], a31[2];
#pragma unroll
        for (int mm = 0; mm < 2; ++mm) {
            const unsigned short* ar = bA + (wrM * 128 + (6 + mm) * 16 + l15) * 64;
            a30[mm] = *(const short8*)(ar + s0);
            a31[mm] = *(const short8*)(ar + s1);
        }
        if (hasn) {
            load_lds_16(gA + (size_t)3 * jstep + kof, &sA[nxt][3 * 4096 + w * 512]);
            __asm__ volatile("s_waitcnt vmcnt(2)" ::: "memory");  // retires next tile's Bj*+Aj0+Aj2
        }
        __builtin_amdgcn_s_barrier();
        __asm__ volatile("s_waitcnt lgkmcnt(0)" ::: "memory");
        __builtin_amdgcn_s_setprio(1);
#pragma unroll
        for (int mm = 0; mm < 2; ++mm)
#pragma unroll
            for (int ni = 0; ni < 3; ++ni) {
                acc[6 + mm][ni] = __builtin_amdgcn_mfma_f32_16x16x32_bf16(a30[mm], bf0[ni], acc[6 + mm][ni], 0, 0, 0);
                acc[6 + mm][ni] = __builtin_amdgcn_mfma_f32_16x16x32_bf16(a31[mm], bf1[ni], acc[6 + mm][ni], 0, 0, 0);
            }
        __builtin_amdgcn_s_setprio(0);
        __builtin_amdgcn_s_barrier();
    }

#pragma unroll
    for (int mi = 0; mi < 8; ++mi)
#pragma unroll
        for (int ni = 0; ni < 3; ++ni)
#pragma unroll
            for (int r = 0; r < 4; ++r) {
                int gr = m0 + wrM * 128 + mi * 16 + quad * 4 + r;
                int gc = n0 + wcN * 48 + ni * 16 + l15;
                C[(size_t)gr * N + gc] = f2bf(acc[mi][ni][r]);
            }
}

// ---------------- GEMM2: 256x128 tile (grid 256, full GPU), 8 waves (4Mx2N) ----------------
__global__ __launch_bounds__(512, 2) void gemm256n128_kernel(const unsigned short* __restrict__ A,
                                                             const unsigned short* __restrict__ Bt,
                                                             float* __restrict__ C,
                                                             int M, int N, int K, int NBX) {
    __shared__ __align__(16) unsigned short sA[2][256 * 64];  // 64 KB
    __shared__ __align__(16) unsigned short sB[2][128 * 64];  // 32 KB
    const int tid = threadIdx.x;
    const int lane = tid & 63, w = tid >> 6;
    const int quad = lane >> 4, l15 = lane & 15;
    const int wrM = w >> 1, wcN = w & 1;

    const int nwg = gridDim.x;
    const int bswz = (blockIdx.x & 7) * (nwg >> 3) + (blockIdx.x >> 3);
    const int m0 = (bswz / NBX) * 256;
    const int n0 = (bswz % NBX) * 128;

    const int lr = tid >> 3;
    const int sc = (tid & 7) ^ (lr & 7);
    const unsigned short* gA = A + (size_t)(m0 + lr) * K + sc * 8;
    const unsigned short* gB = Bt + (size_t)(n0 + lr) * K + sc * 8;
    const size_t jstep = (size_t)64 * K;

    const int s0 = (quad ^ (l15 & 7)) * 8;
    const int s1 = ((4 | quad) ^ (l15 & 7)) * 8;

    f32x4 acc[4][4];
    const f32x4 z4 = {0.f, 0.f, 0.f, 0.f};
#pragma unroll
    for (int mi = 0; mi < 4; ++mi)
#pragma unroll
        for (int ni = 0; ni < 4; ++ni) acc[mi][ni] = z4;

#pragma unroll
    for (int j = 0; j < 4; ++j)
        load_lds_16(gA + (size_t)j * jstep, &sA[0][j * 4096 + w * 512]);
#pragma unroll
    for (int j = 0; j < 2; ++j)
        load_lds_16(gB + (size_t)j * jstep, &sB[0][j * 4096 + w * 512]);

    const int NT = K >> 6;
    for (int kt = 0; kt < NT; ++kt) {
        const int buf = kt & 1;
        const unsigned short* bA = &sA[buf][0];
        const unsigned short* bB = &sB[buf][0];

        __builtin_amdgcn_s_barrier();   // B1
        if (kt + 1 < NT) {
            const size_t kof = (size_t)(kt + 1) * 64;
#pragma unroll
            for (int j = 0; j < 4; ++j)
                load_lds_16(gA + (size_t)j * jstep + kof, &sA[buf ^ 1][j * 4096 + w * 512]);
#pragma unroll
            for (int j = 0; j < 2; ++j)
                load_lds_16(gB + (size_t)j * jstep + kof, &sB[buf ^ 1][j * 4096 + w * 512]);
            __asm__ volatile("s_waitcnt vmcnt(6)" ::: "memory");
        } else {
            __asm__ volatile("s_waitcnt vmcnt(0)" ::: "memory");
        }
        __builtin_amdgcn_s_barrier();   // B2

        short8 bf0[4], bf1[4];
#pragma unroll
        for (int ni = 0; ni < 4; ++ni) {
            const unsigned short* br = bB + (wcN * 64 + ni * 16 + l15) * 64;
            bf0[ni] = *(const short8*)(br + s0);
            bf1[ni] = *(const short8*)(br + s1);
        }
#pragma unroll
        for (int ph = 0; ph < 4; ++ph) {
            short8 af0, af1;
            {
                const unsigned short* ar = bA + (wrM * 64 + ph * 16 + l15) * 64;
                af0 = *(const short8*)(ar + s0);
                af1 = *(const short8*)(ar + s1);
            }
#pragma unroll
            for (int ni = 0; ni < 4; ++ni) {
                acc[ph][ni] = __builtin_amdgcn_mfma_f32_16x16x32_bf16(af0, bf0[ni], acc[ph][ni], 0, 0, 0);
                acc[ph][ni] = __builtin_amdgcn_mfma_f32_16x16x32_bf16(af1, bf1[ni], acc[ph][ni], 0, 0, 0);
            }
        }
    }

#pragma unroll
    for (int mi = 0; mi < 4; ++mi)
#pragma unroll
        for (int ni = 0; ni < 4; ++ni)
#pragma unroll
            for (int r = 0; r < 4; ++r) {
                int gr = m0 + wrM * 64 + mi * 16 + quad * 4 + r;
                int gc = n0 + wcN * 64 + ni * 16 + l15;
                C[(size_t)gr * N + gc] = acc[mi][ni][r];
            }
}

// ---------------- RoPE for Q,K (Q pre-scaled by 1/sqrt(d) * log2(e)) ----------------
#define QP (MROWS * NHEADS * 64)  // 4194304
#define KP (MROWS * NKV * 64)     // 1048576
#define QSCL (0.08838834764831845f * 1.4426950408889634f)
__global__ void rope_kernel(const unsigned short* __restrict__ qkv,
                            const float* __restrict__ cosb, const float* __restrict__ sinb,
                            unsigned short* __restrict__ Q, unsigned short* __restrict__ K) {
    int tid = blockIdx.x * 256 + threadIdx.x;
    if (tid < QP) {
        int d = tid & 63;
        int h = (tid >> 6) & 15;
        int row = tid >> 10;
        int t = row & (TT - 1), b = row >> 11;
        float x1 = b2f(qkv[(size_t)row * NQKV + h * 128 + d]);
        float x2 = b2f(qkv[(size_t)row * NQKV + h * 128 + d + 64]);
        float c = cosb[t * 64 + d], s = sinb[t * 64 + d];
        unsigned short* dst = Q + ((size_t)(b * NHEADS + h) * TT + t) * 128 + d;
        dst[0]  = f2bf((x1 * c - x2 * s) * QSCL);
        dst[64] = f2bf((x2 * c + x1 * s) * QSCL);
    } else {
        int p = tid - QP;
        int d = p & 63;
        int kh = (p >> 6) & 3;
        int row = p >> 8;
        int t = row & (TT - 1), b = row >> 11;
        float x1 = b2f(qkv[(size_t)row * NQKV + 2048 + kh * 128 + d]);
        float x2 = b2f(qkv[(size_t)row * NQKV + 2048 + kh * 128 + d + 64]);
        float c = cosb[t * 64 + d], s = sinb[t * 64 + d];
        unsigned short* dst = K + ((size_t)(b * NKV + kh) * TT + t) * 128 + d;
        dst[0]  = f2bf(x1 * c - x2 * s);
        dst[64] = f2bf(x2 * c + x1 * s);
    }
}

// ---------------- V transpose: qkv -> Vt[b][kvh][d][T] ----------------
__global__ void vtrans_kernel(const unsigned short* __restrict__ qkv,
                              unsigned short* __restrict__ Vt) {
    __shared__ unsigned short tile[32][33];
    int t0 = blockIdx.x * 32, d0 = blockIdx.y * 32, bz = blockIdx.z;  // bz = b*NKV+kh
    int b = bz >> 2, kh = bz & 3;
    int tx = threadIdx.x, ty = threadIdx.y;
#pragma unroll
    for (int i = 0; i < 32; i += 8)
        tile[ty + i][tx] = qkv[(size_t)(b * TT + t0 + ty + i) * NQKV + 2560 + kh * 128 + d0 + tx];
    __syncthreads();
#pragma unroll
    for (int i = 0; i < 32; i += 8)
        Vt[((size_t)bz * 128 + d0 + ty + i) * TT + t0 + tx] = tile[tx][ty + i];
}

// ---------------- flash attention: trio grid, 48 KB LDS (3 blk/CU), reg-P via shfl ----------
__global__ __launch_bounds__(256, 3) void flash_kernel(const unsigned short* __restrict__ Qb,
                                                       const unsigned short* __restrict__ Kb,
                                                       const unsigned short* __restrict__ Vtb,
                                                       unsigned short* __restrict__ Ob,
                                                       unsigned short* __restrict__ Po,
                                                       float* __restrict__ Pl) {
    __shared__ __align__(16) unsigned short sK[2][64 * 128];  // [buf][kv][d] 32 KB
    __shared__ __align__(16) unsigned short sV[128 * 64];     // [d][kv]      16 KB

    const int tid = threadIdx.x;
    const int w = tid >> 6, lane = tid & 63;
    const int quad = lane >> 4, l15 = lane & 15;
    const int r7 = l15 & 7;

    const int lin = blockIdx.x;
    const int member = lin >> 8;
    const int rem = lin & 255;
    const int h = rem & 15;
    const int b = (rem >> 4) & 1;
    const int j = rem >> 5;           // 0..7
    int qb, kvlo, kvhi;
    bool partial;
    if (member == 2) {
        qb = j; kvlo = 0; kvhi = (qb + 1) * 128; partial = false;
    } else {
        qb = 15 - j;
        int half = (qb + 1) * 64;
        kvlo = member ? half : 0;
        kvhi = member ? (qb + 1) * 128 : half;
        partial = true;
    }
    const int q0 = qb * 128;
    const int ntile = (kvhi - kvlo) >> 6;
    const int kvh = h >> 2;
    const unsigned short* Qh = Qb + (size_t)(b * NHEADS + h) * TT * 128;
    const unsigned short* Kh = Kb + (size_t)(b * NKV + kvh) * TT * 128;
    const unsigned short* Vth = Vtb + (size_t)(b * NKV + kvh) * 128 * TT;

    const int wrow0 = q0 + w * 32;

    const int kr = lane >> 4;
    const unsigned short* gKe = Kh + (size_t)(w * 16 + kr) * 128 + (((lane & 15) ^ kr) * 8);
    const unsigned short* gKo = Kh + (size_t)(w * 16 + 4 + kr) * 128 + (((lane & 15) ^ (4 + kr)) * 8);
    const int vr = lane >> 3;
    const unsigned short* gV0 = Vth + (size_t)(w * 32 + vr) * TT + (((lane & 7) ^ vr) * 8);

    short8 aq[2][4];
#pragma unroll
    for (int mi = 0; mi < 2; ++mi)
#pragma unroll
        for (int dk = 0; dk < 4; ++dk)
            aq[mi][dk] = *(const short8*)(Qh + (size_t)(wrow0 + mi * 16 + l15) * 128 + dk * 32 + quad * 8);

    f32x4 accO[2][8];
    float accLc[2] = {0.f, 0.f};
    const f32x4 z4 = {0.f, 0.f, 0.f, 0.f};
#pragma unroll
    for (int mi = 0; mi < 2; ++mi)
#pragma unroll
        for (int nb = 0; nb < 8; ++nb) accO[mi][nb] = z4;

    // prologue: K(first tile) -> sK[0]
#pragma unroll
    for (int g = 0; g < 4; ++g) {
        const unsigned short* src = (g & 1) ? gKo : gKe;
        load_lds_16(src + (size_t)(kvlo + (g >> 1) * 8) * 128, &sK[0][(w * 4 + g) * 512]);
    }

    for (int it = 0; it < ntile; ++it) {
        const int cur = it & 1;
        const int kv0 = kvlo + it * 64;
        __asm__ volatile("s_waitcnt vmcnt(0)" ::: "memory");
        __builtin_amdgcn_s_barrier();
#pragma unroll
        for (int g = 0; g < 4; ++g)
            load_lds_16(gV0 + (size_t)(g * 8) * TT + kv0, &sV[(w * 4 + g) * 512]);
        const bool hasn = (it + 1 < ntile);
        if (hasn) {
#pragma unroll
            for (int g = 0; g < 4; ++g) {
                const unsigned short* src = (g & 1) ? gKo : gKe;
                load_lds_16(src + (size_t)(kv0 + 64 + (g >> 1) * 8) * 128, &sK[cur ^ 1][(w * 4 + g) * 512]);
            }
        }
        const bool compute = (kv0 <= wrow0 + 31);  // wave-uniform
        short8 ap[2][2];
        if (compute) {
            f32x4 st[4][2];
#pragma unroll
            for (int t = 0; t < 4; ++t)
#pragma unroll
                for (int h2 = 0; h2 < 2; ++h2) st[t][h2] = z4;
            __builtin_amdgcn_s_setprio(1);
#pragma unroll
            for (int t = 0; t < 4; ++t) {
#pragma unroll
                for (int dk = 0; dk < 4; ++dk) {
                    short8 ak = *(const short8*)(&sK[cur][(t * 16 + l15) * 128 + ((dk * 4 + quad) ^ r7) * 8]);
                    st[t][0] = __builtin_amdgcn_mfma_f32_16x16x32_bf16(ak, aq[0][dk], st[t][0], 0, 0, 0);
                    st[t][1] = __builtin_amdgcn_mfma_f32_16x16x32_bf16(ak, aq[1][dk], st[t][1], 0, 0, 0);
                }
            }
            __builtin_amdgcn_s_setprio(0);
            unsigned int pk32[4][2][2];
#pragma unroll
            for (int h2 = 0; h2 < 2; ++h2) {
                const int qg = wrow0 + h2 * 16 + l15;
#pragma unroll
                for (int t = 0; t < 4; ++t) {
                    const int kvb = kv0 + t * 16 + quad * 4;
                    const bool nm = (kv0 + t * 16 + 15) > (wrow0 + h2 * 16);
                    float pv[4];
#pragma unroll
                    for (int r = 0; r < 4; ++r) {
                        float p = EXP2F(st[t][h2][r]);
                        if (nm) p = (kvb + r <= qg) ? p : 0.f;
                        pv[r] = p;
                    }
                    accLc[h2] += (pv[0] + pv[1]) + (pv[2] + pv[3]);
                    __asm__("v_cvt_pk_bf16_f32 %0, %1, %2" : "=v"(pk32[t][h2][0]) : "v"(pv[0]), "v"(pv[1]));
                    __asm__("v_cvt_pk_bf16_f32 %0, %1, %2" : "=v"(pk32[t][h2][1]) : "v"(pv[2]), "v"(pv[3]));
                }
            }
#pragma unroll
            for (int h2 = 0; h2 < 2; ++h2)
#pragma unroll
                for (int kf = 0; kf < 2; ++kf) {
                    union { unsigned int u[4]; short8 s8; } W;
#pragma unroll
                    for (int wdx = 0; wdx < 4; ++wdx) {
                        int srcl = (2 * (quad & 1) + (wdx >> 1)) * 16 + l15;
                        unsigned int a0 = (unsigned int)__shfl((int)pk32[2 * kf][h2][wdx & 1], srcl, 64);
                        unsigned int a1 = (unsigned int)__shfl((int)pk32[2 * kf + 1][h2][wdx & 1], srcl, 64);
                        W.u[wdx] = (quad >> 1) ? a1 : a0;
                    }
                    ap[h2][kf] = W.s8;
                }
        }
        if (hasn) { __asm__ volatile("s_waitcnt vmcnt(4)" ::: "memory"); }
        else      { __asm__ volatile("s_waitcnt vmcnt(0)" ::: "memory"); }
        __builtin_amdgcn_s_barrier();
        if (compute) {
            __builtin_amdgcn_s_setprio(1);
#pragma unroll
            for (int nb = 0; nb < 8; ++nb) {
                short8 bv0 = *(const short8*)(&sV[(nb * 16 + l15) * 64 + ((quad) ^ r7) * 8]);
                short8 bv1 = *(const short8*)(&sV[(nb * 16 + l15) * 64 + ((4 + quad) ^ r7) * 8]);
#pragma unroll
                for (int mi = 0; mi < 2; ++mi) {
                    accO[mi][nb] = __builtin_amdgcn_mfma_f32_16x16x32_bf16(ap[mi][0], bv0, accO[mi][nb], 0, 0, 0);
                    accO[mi][nb] = __builtin_amdgcn_mfma_f32_16x16x32_bf16(ap[mi][1], bv1, accO[mi][nb], 0, 0, 0);
                }
            }
            __builtin_amdgcn_s_setprio(0);
        }
    }

    float Lr[2][4];
#pragma unroll
    for (int mi = 0; mi < 2; ++mi) {
        float v = accLc[mi];
        v += __shfl_xor(v, 16, 64);
        v += __shfl_xor(v, 32, 64);
#pragma unroll
        for (int r = 0; r < 4; ++r)
            Lr[mi][r] = __shfl(v, quad * 4 + r, 64);
    }

    __syncthreads();
    unsigned short* sPw = &sV[0] + w * 2048;

    if (!partial) {
        float inv[2][4];
#pragma unroll
        for (int mi = 0; mi < 2; ++mi)
#pragma unroll
            for (int r = 0; r < 4; ++r) inv[mi][r] = 1.0f / Lr[mi][r];
        const size_t obase = ((size_t)b * TT + wrow0) * (NHEADS * HEAD_DIM) + h * 128;
#pragma unroll
        for (int half = 0; half < 2; ++half) {
            __asm__ volatile("s_waitcnt lgkmcnt(0)" ::: "memory");
#pragma unroll
            for (int mi = 0; mi < 2; ++mi)
#pragma unroll
                for (int nb2 = 0; nb2 < 4; ++nb2)
#pragma unroll
                    for (int r = 0; r < 4; ++r) {
                        const int row = mi * 16 + quad * 4 + r;
                        sPw[row * 64 + (((2 * nb2 + (l15 >> 3)) ^ (row & 7)) * 8) + r7] =
                            f2bf(accO[mi][half * 4 + nb2][r] * inv[mi][r]);
                    }
            __asm__ volatile("s_waitcnt lgkmcnt(0)" ::: "memory");
#pragma unroll
            for (int pass = 0; pass < 4; ++pass) {
                int row2 = pass * 8 + (lane >> 3);
                short8 vv = *(const short8*)(&sPw[row2 * 64 + (((lane & 7) ^ (row2 & 7)) * 8)]);
                *(short8*)(Ob + obase + (size_t)row2 * (NHEADS * HEAD_DIM) + half * 64 + (lane & 7) * 8) = vv;
            }
        }
    } else {
        const size_t pbase = ((size_t)(member * 2 + b) * 1024 + (wrow0 - 1024)) * 2048 + h * 128;
#pragma unroll
        for (int half = 0; half < 2; ++half) {
            __asm__ volatile("s_waitcnt lgkmcnt(0)" ::: "memory");
#pragma unroll
            for (int mi = 0; mi < 2; ++mi)
#pragma unroll
                for (int nb2 = 0; nb2 < 4; ++nb2)
#pragma unroll
                    for (int r = 0; r < 4; ++r) {
                        const int row = mi * 16 + quad * 4 + r;
                        sPw[row * 64 + (((2 * nb2 + (l15 >> 3)) ^ (row & 7)) * 8) + r7] =
                            f2bf(accO[mi][half * 4 + nb2][r]);
                    }
            __asm__ volatile("s_waitcnt lgkmcnt(0)" ::: "memory");
#pragma unroll
            for (int pass = 0; pass < 4; ++pass) {
                int row2 = pass * 8 + (lane >> 3);
                short8 vv = *(const short8*)(&sPw[row2 * 64 + (((lane & 7) ^ (row2 & 7)) * 8)]);
                *(short8*)(Po + pbase + (size_t)row2 * 2048 + half * 64 + (lane & 7) * 8) = vv;
            }
        }
        float* plb = Pl + ((size_t)(member * 2 + b) * 16 + h) * 1024 + (wrow0 - 1024);
        if (l15 == 0) {
#pragma unroll
            for (int mi = 0; mi < 2; ++mi)
#pragma unroll
                for (int r = 0; r < 4; ++r)
                    plb[mi * 16 + quad * 4 + r] = Lr[mi][r];
        }
    }
}

// ---------------- merge: attn[rows 1024..2047] = (O0+O1)/(L0+L1) ----------------
__global__ void merge_kernel(const unsigned short* __restrict__ Po, const float* __restrict__ Pl,
                             unsigned short* __restrict__ attn) {
    int gid = blockIdx.x * 256 + threadIdx.x;
    size_t e8 = (size_t)gid * 8;
    int col = (int)(e8 & 2047);
    int rl  = (int)((e8 >> 11) & 1023);
    int b   = (int)(e8 >> 21);
    int h   = col >> 7;
    size_t i0 = ((size_t)b * 1024 + rl) * 2048 + col;            // part 0
    size_t i1 = ((size_t)(2 + b) * 1024 + rl) * 2048 + col;      // part 1
    float l = Pl[((size_t)b * 16 + h) * 1024 + rl] + Pl[((size_t)(2 + b) * 16 + h) * 1024 + rl];
    float inv = 1.0f / l;
    union { uint4 v; unsigned short u[8]; } a, c, o;
    a.v = *(const uint4*)(Po + i0);
    c.v = *(const uint4*)(Po + i1);
#pragma unroll
    for (int k = 0; k < 8; ++k)
        o.u[k] = f2bf((b2f(a.u[k]) + b2f(c.u[k])) * inv);
    *(uint4*)(attn + ((size_t)b * 2048 + 1024 + rl) * 2048 + col) = o.v;
}

// ---------------- launch ----------------
extern "C" void kernel_launch(void* const* d_in, const int* in_sizes, int n_in,
                              void* d_out, int out_size, void* d_ws, size_t ws_size,
                              hipStream_t stream) {
    const float* x    = (const float*)d_in[0];
    const float* cosb = (const float*)d_in[1];
    const float* sinb = (const float*)d_in[2];
    const float* wq   = (const float*)d_in[3];
    const float* wk   = (const float*)d_in[4];
    const float* wv   = (const float*)d_in[5];
    const float* wo   = (const float*)d_in[6];
    float* out = (float*)d_out;

    char* ws = (char*)d_ws;
    unsigned short* xb    = (unsigned short*)(ws);                       // 16 MB (dead after gemm1)
    unsigned short* wqkvT = (unsigned short*)(ws + (16u << 20));         // 12 MB (dead after gemm1)
    unsigned short* woT   = (unsigned short*)(ws + (28u << 20));         // 8 MB
    unsigned short* qkv   = (unsigned short*)(ws + (36u << 20));         // 24 MB
    unsigned short* Qbuf  = (unsigned short*)(ws + (60u << 20));         // 16 MB
    unsigned short* Kbuf  = (unsigned short*)(ws + (76u << 20));         // 4 MB
    unsigned short* Vt    = (unsigned short*)(ws + (80u << 20));         // 4 MB
    unsigned short* attn  = (unsigned short*)(ws + (84u << 20));         // 16 MB -> 100 MB total
    // overlays (regions dead by the time flash runs):
    unsigned short* Po    = (unsigned short*)(ws);                       // 16 MB partial O (over xb)
    float*          Pl    = (float*)(ws + (16u << 20));                  // 512 KB partial L (over wqkvT)

    cast_x_kernel<<<(MROWS * HIDDEN) / 4 / 256, 256, 0, stream>>>(x, xb);
    pack_wqkvT_kernel<<<dim3(NQKV / 32, HIDDEN / 32), dim3(32, 8), 0, stream>>>(wq, wk, wv, wqkvT);
    pack_woT_kernel<<<dim3(HIDDEN / 32, HIDDEN / 32), dim3(32, 8), 0, stream>>>(wo, woT);

    // GEMM1: 4096x3072x2048 -> 256x192 tiles = 16x16 = 256 blocks (full GPU, %8==0)
    gemm192_kernel<<<dim3(256), 512, 0, stream>>>(xb, wqkvT, qkv);

    rope_kernel<<<(QP + KP) / 256, 256, 0, stream>>>(qkv, cosb, sinb, Qbuf, Kbuf);
    vtrans_kernel<<<dim3(TT / 32, HEAD_DIM / 32, BB * NKV), dim3(32, 8), 0, stream>>>(qkv, Vt);

    // flash: trio grid 768 (members 0/1 partial halves, member 2 direct), 3 blocks/CU
    flash_kernel<<<dim3(768), 256, 0, stream>>>(Qbuf, Kbuf, Vt, attn, Po, Pl);
    merge_kernel<<<dim3(2048), 256, 0, stream>>>(Po, Pl, attn);

    // GEMM2: 4096x2048x2048 -> 256x128 tiles = 16x16 = 256 blocks (full GPU, %8==0)
    gemm256n128_kernel<<<dim3((MROWS / 256) * (HIDDEN / 128)), 512, 0, stream>>>(
        attn, woT, out, MROWS, HIDDEN, HIDDEN, HIDDEN / 128);
}